// Round 11
// baseline (132.190 us; speedup 1.0000x reference)
//
#include <hip/hip_runtime.h>
#include <hip/hip_bf16.h>

#define S_LEN 2048
#define BATCH 2
#define DMODEL 1024
#define NHEAD 16
#define DHEAD 64
#define WINDOW 256
#define MROWS (S_LEN * BATCH)   // 4096

typedef unsigned short u16;
typedef unsigned int u32;
typedef __attribute__((ext_vector_type(8))) short bf16x8;
typedef __attribute__((ext_vector_type(4))) float f32x4;
typedef __attribute__((ext_vector_type(2))) unsigned int u32x2;

typedef const __attribute__((address_space(1))) void gvoid;
typedef __attribute__((address_space(3))) void lvoid;

__device__ __forceinline__ float b2f(u16 u) {
    union { unsigned int i; float f; } x; x.i = ((unsigned int)u) << 16; return x.f;
}
__device__ __forceinline__ u16 f2b(float f) {
    union { float f; unsigned int i; } x; x.f = f;
    unsigned int r = x.i + 0x7fffu + ((x.i >> 16) & 1u);
    return (u16)(r >> 16);
}
__device__ __forceinline__ u32 cvtpk(float a, float b) {
    u32 r; asm("v_cvt_pk_bf16_f32 %0, %1, %2" : "=v"(r) : "v"(a), "v"(b)); return r;
}
__device__ __forceinline__ bf16x8 ld8f(const float* __restrict__ p) {
    bf16x8 r;
    #pragma unroll
    for (int i = 0; i < 8; i++) r[i] = (short)f2b(p[i]);
    return r;
}
template<bool BF>
__device__ __forceinline__ bf16x8 ldrow(const void* __restrict__ base, size_t elemOff) {
    if constexpr (BF) return *reinterpret_cast<const bf16x8*>((const u16*)base + elemOff);
    else              return ld8f((const float*)base + elemOff);
}

// Streaming cast with CHANNEL-SWIZZLED writes: within each 1024-elem row,
// 128-elem (256B) block index bits [9:7] are XORed with (row & 7).
// All consumers read with the same swizzle. 8-elem runs never cross a block.
__global__ __launch_bounds__(256) void cast_all(
    const float* __restrict__ x,  const float* __restrict__ Wq,
    const float* __restrict__ Wk, const float* __restrict__ Wv,
    const float* __restrict__ Wo,
    u16* __restrict__ xb, u16* __restrict__ wb, u16* __restrict__ wob)
{
    const size_t idx = ((size_t)blockIdx.x * 256 + threadIdx.x) * 8;
    const size_t M1 = 1048576;
    const size_t sw = ((idx >> 10) & 7) << 7;   // panel bases are 1024-row aligned
    const float* src; u16* dst;
    if (idx < 4 * M1)      { src = x  + idx;            dst = xb  + ((idx)          ^ sw); }
    else if (idx < 5 * M1) { src = Wq + (idx - 4 * M1); dst = wb  + ((idx - 4 * M1) ^ sw); }
    else if (idx < 6 * M1) { src = Wk + (idx - 5 * M1); dst = wb  + ((idx - 4 * M1) ^ sw); }
    else if (idx < 7 * M1) { src = Wv + (idx - 6 * M1); dst = wb  + ((idx - 4 * M1) ^ sw); }
    else                   { src = Wo + (idx - 7 * M1); dst = wob + ((idx - 7 * M1) ^ sw); }
    *reinterpret_cast<bf16x8*>(dst) = ld8f(src);
}

// ---------------- m97-structure staged GEMMs, channel-swizzled sources ----------------
// Inputs xb/wb are channel-swizzled; staging reads use (kk ^ arswz) so LDS
// contents are identical to the unswizzled version. LDS bank swizzle as before.

__global__ __launch_bounds__(256) void gemm_qkv_s(
    const u16* __restrict__ A, const u16* __restrict__ Wall,
    const float* __restrict__ bq, const float* __restrict__ bk, const float* __restrict__ bv,
    const float* __restrict__ beta,
    u16* __restrict__ qbuf, u16* __restrict__ kbuf, u16* __restrict__ vt)
{
    __shared__ u16 lA[128 * 32];
    __shared__ u16 lB[128 * 32];
    const int tid = threadIdx.x;
    const int lane = tid & 63, wave = tid >> 6;
    const int r15 = lane & 15, g = lane >> 4;
    const int m0 = blockIdx.x * 128;
    const int range = blockIdx.y >> 3;                       // 0=Q 1=K 2=V
    const int n0 = (blockIdx.y & 7) * 128;                   // local col
    const u16* W = Wall + (size_t)range * DMODEL * DMODEL;
    const float* bias = (range == 0) ? bq : (range == 1) ? bk : bv;

    const int srow = tid >> 2;
    const int sslot = (tid & 3) ^ ((tid >> 3) & 3);          // LDS-bank pre-swizzle
    const int arswz = ((srow & 7) << 7);                     // channel de-alias
    const u16* aSrc = A + (size_t)(m0 + srow) * DMODEL + sslot * 8;
    const u16* wSrc = W + (size_t)(n0 + srow) * DMODEL + sslot * 8;
    const int ldsW = wave * 1024;
    const int mrow = (wave >> 1) * 64, nrow = (wave & 1) * 64;
    const int swz = (g ^ ((r15 >> 1) & 3)) << 4;
    const char* lAr = (const char*)lA + swz;
    const char* lBr = (const char*)lB + swz;

    f32x4 acc[4][4] = {};
    for (int kk = 0; kk < DMODEL; kk += 32) {
        const int kks = kk ^ arswz;
        __syncthreads();
        #pragma unroll
        for (int ro = 0; ro < 2; ro++) {
            __builtin_amdgcn_global_load_lds(
                (gvoid*)(aSrc + (size_t)ro * 64 * DMODEL + kks),
                (lvoid*)((char*)lA + ro * 4096 + ldsW), 16, 0, 0);
            __builtin_amdgcn_global_load_lds(
                (gvoid*)(wSrc + (size_t)ro * 64 * DMODEL + kks),
                (lvoid*)((char*)lB + ro * 4096 + ldsW), 16, 0, 0);
        }
        __syncthreads();
        bf16x8 af[4], bf[4];
        #pragma unroll
        for (int mi = 0; mi < 4; mi++)
            af[mi] = *reinterpret_cast<const bf16x8*>(lAr + ((mrow + mi * 16 + r15) << 6));
        #pragma unroll
        for (int ni = 0; ni < 4; ni++)
            bf[ni] = *reinterpret_cast<const bf16x8*>(lBr + ((nrow + ni * 16 + r15) << 6));
        #pragma unroll
        for (int mi = 0; mi < 4; mi++)
            #pragma unroll
            for (int ni = 0; ni < 4; ni++)
                acc[mi][ni] = __builtin_amdgcn_mfma_f32_16x16x32_bf16(
                    af[mi], bf[ni], acc[mi][ni], 0, 0, 0);
    }
    #pragma unroll
    for (int ni = 0; ni < 4; ni++) {
        const int col = n0 + nrow + ni * 16 + r15;           // 0..1023
        const float bv_ = bias[col];
        float scale = 1.0f;
        if (range == 0) scale = 1.0f / (8.0f * __expf(beta[col >> 6]));
        #pragma unroll
        for (int mi = 0; mi < 4; mi++)
            #pragma unroll
            for (int r = 0; r < 4; r++) {
                const int row = m0 + mrow + mi * 16 + g * 4 + r;  // = s*BATCH+b
                const int s = row >> 1;
                const float val = acc[mi][ni][r] + bv_;
                if (range == 0) {
                    qbuf[(size_t)row * DMODEL + (col ^ ((s & 7) << 7))] = f2b(val * scale);
                } else if (range == 1) {
                    kbuf[(size_t)row * DMODEL + (col ^ ((s & 7) << 7))] = f2b(val);
                } else {
                    const int b = row & 1;
                    vt[((size_t)(b * NHEAD + (col >> 6)) * DHEAD + (col & 63)) * S_LEN
                       + (s ^ ((col & 7) << 7))] = f2b(val);
                }
            }
    }
}

// abuf and wob are channel-swizzled; staging reads de-swizzle via (kk ^ arswz).
__global__ __launch_bounds__(256) void gemm_out_s(
    const u16* __restrict__ A, const u16* __restrict__ W,
    const float* __restrict__ bias, float* __restrict__ C)
{
    __shared__ u16 lA[128 * 32];
    __shared__ u16 lB[128 * 32];
    const int tid = threadIdx.x;
    const int lane = tid & 63, wave = tid >> 6;
    const int r15 = lane & 15, g = lane >> 4;
    const int m0 = blockIdx.x * 128;
    const int n0 = blockIdx.y * 128;

    const int srow = tid >> 2;
    const int sslot = (tid & 3) ^ ((tid >> 3) & 3);
    const int arswz = ((srow & 7) << 7);
    const u16* aSrc = A + (size_t)(m0 + srow) * DMODEL + sslot * 8;
    const u16* wSrc = W + (size_t)(n0 + srow) * DMODEL + sslot * 8;
    const int ldsW = wave * 1024;
    const int mrow = (wave >> 1) * 64, nrow = (wave & 1) * 64;
    const int swz = (g ^ ((r15 >> 1) & 3)) << 4;
    const char* lAr = (const char*)lA + swz;
    const char* lBr = (const char*)lB + swz;

    f32x4 acc[4][4] = {};
    for (int kk = 0; kk < DMODEL; kk += 32) {
        const int kks = kk ^ arswz;
        __syncthreads();
        #pragma unroll
        for (int ro = 0; ro < 2; ro++) {
            __builtin_amdgcn_global_load_lds(
                (gvoid*)(aSrc + (size_t)ro * 64 * DMODEL + kks),
                (lvoid*)((char*)lA + ro * 4096 + ldsW), 16, 0, 0);
            __builtin_amdgcn_global_load_lds(
                (gvoid*)(wSrc + (size_t)ro * 64 * DMODEL + kks),
                (lvoid*)((char*)lB + ro * 4096 + ldsW), 16, 0, 0);
        }
        __syncthreads();
        bf16x8 af[4], bf[4];
        #pragma unroll
        for (int mi = 0; mi < 4; mi++)
            af[mi] = *reinterpret_cast<const bf16x8*>(lAr + ((mrow + mi * 16 + r15) << 6));
        #pragma unroll
        for (int ni = 0; ni < 4; ni++)
            bf[ni] = *reinterpret_cast<const bf16x8*>(lBr + ((nrow + ni * 16 + r15) << 6));
        #pragma unroll
        for (int mi = 0; mi < 4; mi++)
            #pragma unroll
            for (int ni = 0; ni < 4; ni++)
                acc[mi][ni] = __builtin_amdgcn_mfma_f32_16x16x32_bf16(
                    af[mi], bf[ni], acc[mi][ni], 0, 0, 0);
    }
    #pragma unroll
    for (int ni = 0; ni < 4; ni++) {
        const int col = n0 + nrow + ni * 16 + r15;
        const float bv_ = bias[col];
        #pragma unroll
        for (int mi = 0; mi < 4; mi++)
            #pragma unroll
            for (int r = 0; r < 4; r++) {
                const int row = m0 + mrow + mi * 16 + g * 4 + r;
                C[(size_t)row * DMODEL + col] = acc[mi][ni][r] + bv_;
            }
    }
}

// ---------------- fallback (fp32 direct, unswizzled) GEMMs ----------------
template<bool ABF, bool WBF>
__global__ __launch_bounds__(256) void gemm_qkv_t(
    const void* __restrict__ A_,
    const void* __restrict__ Wq_, const void* __restrict__ Wk_, const void* __restrict__ Wv_,
    const float* __restrict__ bq, const float* __restrict__ bk, const float* __restrict__ bv,
    const float* __restrict__ beta,
    u16* __restrict__ qbuf, u16* __restrict__ kbuf, u16* __restrict__ vt)
{
    const int lane = threadIdx.x & 63;
    const int wave = threadIdx.x >> 6;
    const int r15 = lane & 15, g = lane >> 4;
    const int m0 = blockIdx.x * 128 + (wave >> 1) * 64;
    const int range = blockIdx.y >> 3;
    const int n0 = (blockIdx.y & 7) * 128 + (wave & 1) * 64;
    const void* W_ = (range == 0) ? Wq_ : (range == 1) ? Wk_ : Wv_;
    const float* bias = (range == 0) ? bq : (range == 1) ? bk : bv;
    const size_t aBase = (size_t)(m0 + r15) * DMODEL + g * 8;
    const size_t wBase = (size_t)(n0 + r15) * DMODEL + g * 8;
    f32x4 acc[4][4] = {};
    for (int k = 0; k < DMODEL; k += 32) {
        bf16x8 af[4], bf[4];
        #pragma unroll
        for (int mi = 0; mi < 4; mi++) af[mi] = ldrow<ABF>(A_, aBase + (size_t)mi * 16 * DMODEL + k);
        #pragma unroll
        for (int ni = 0; ni < 4; ni++) bf[ni] = ldrow<WBF>(W_, wBase + (size_t)ni * 16 * DMODEL + k);
        #pragma unroll
        for (int mi = 0; mi < 4; mi++)
            #pragma unroll
            for (int ni = 0; ni < 4; ni++)
                acc[mi][ni] = __builtin_amdgcn_mfma_f32_16x16x32_bf16(
                    af[mi], bf[ni], acc[mi][ni], 0, 0, 0);
    }
    #pragma unroll
    for (int ni = 0; ni < 4; ni++) {
        const int col = n0 + ni * 16 + r15;
        const float bv_ = bias[col];
        float scale = 1.0f;
        if (range == 0) scale = 1.0f / (8.0f * __expf(beta[col >> 6]));
        #pragma unroll
        for (int mi = 0; mi < 4; mi++)
            #pragma unroll
            for (int r = 0; r < 4; r++) {
                const int row = m0 + mi * 16 + g * 4 + r;
                const float val = acc[mi][ni][r] + bv_;
                if (range == 0) {
                    qbuf[(size_t)row * DMODEL + col] = f2b(val * scale);
                } else if (range == 1) {
                    kbuf[(size_t)row * DMODEL + col] = f2b(val);
                } else {
                    const int b = row & 1, s = row >> 1;
                    vt[((size_t)(b * NHEAD + (col >> 6)) * DHEAD + (col & 63)) * S_LEN + s]
                        = f2b(val);
                }
            }
    }
}

template<bool WBF>
__global__ __launch_bounds__(256) void gemm_out_t(
    const u16* __restrict__ A, const void* __restrict__ W_,
    const float* __restrict__ bias, float* __restrict__ C)
{
    const int lane = threadIdx.x & 63;
    const int wave = threadIdx.x >> 6;
    const int r15 = lane & 15, g = lane >> 4;
    const int m0 = blockIdx.x * 64 + (wave >> 1) * 32;
    const int n0 = blockIdx.y * 128 + (wave & 1) * 64;
    const u16* a0 = A + (size_t)(m0 + r15) * DMODEL + g * 8;
    const size_t wBase = (size_t)(n0 + r15) * DMODEL + g * 8;
    f32x4 acc[2][4] = {};
    for (int k = 0; k < DMODEL; k += 32) {
        bf16x8 af[2], bf[4];
        #pragma unroll
        for (int mi = 0; mi < 2; mi++)
            af[mi] = *reinterpret_cast<const bf16x8*>(a0 + (size_t)mi * 16 * DMODEL + k);
        #pragma unroll
        for (int ni = 0; ni < 4; ni++) bf[ni] = ldrow<WBF>(W_, wBase + (size_t)ni * 16 * DMODEL + k);
        #pragma unroll
        for (int mi = 0; mi < 2; mi++)
            #pragma unroll
            for (int ni = 0; ni < 4; ni++)
                acc[mi][ni] = __builtin_amdgcn_mfma_f32_16x16x32_bf16(
                    af[mi], bf[ni], acc[mi][ni], 0, 0, 0);
    }
    #pragma unroll
    for (int ni = 0; ni < 4; ni++) {
        const int col = n0 + ni * 16 + r15;
        const float bv_ = bias[col];
        #pragma unroll
        for (int mi = 0; mi < 2; mi++)
            #pragma unroll
            for (int r = 0; r < 4; r++) {
                const int row = m0 + mi * 16 + g * 4 + r;
                C[(size_t)row * DMODEL + col] = acc[mi][ni][r] + bv_;
            }
    }
}

// Sliding-window attention v5: attn3 structure + channel-swizzled Q/K/V/O
// addressing (SWZ) + double-buffered P-LDS (breaks chunk WAR serialization).
template<bool SWZ>
__global__ __launch_bounds__(256) void attn5(
    const u16* __restrict__ qb, const u16* __restrict__ kb_,
    const u16* __restrict__ vt, u16* __restrict__ O)
{
    __shared__ u16 plds[2][4][16][64];   // 16KB, double-buffered per chunk
    const int lane = threadIdx.x & 63;
    const int wave = threadIdx.x >> 6;
    const int bid  = blockIdx.x;
    const int sbid = (bid & 7) * 128 + (bid >> 3);           // XCD-chunked (1024%8==0)
    const int wid = sbid * 4 + wave;
    const int qt = wid & (S_LEN / 16 - 1);
    const int h  = (wid >> 7) & (NHEAD - 1);
    const int b  = wid >> 11;
    const int qstart = qt * 16;
    const int r15 = lane & 15, g = lane >> 4;
    const int i_glob = qstart + r15;
    const int sw7 = SWZ ? ((r15 & 7) << 7) : 0;

    const u16* qrow = qb + ((size_t)i_glob * BATCH + b) * DMODEL + ((h * DHEAD) ^ sw7);
    const bf16x8 qf0 = *reinterpret_cast<const bf16x8*>(qrow + g * 8);
    const bf16x8 qf1 = *reinterpret_cast<const bf16x8*>(qrow + 32 + g * 8);
    const u16* vbase = vt + (size_t)(b * NHEAD + h) * DHEAD * S_LEN;

    const int q7 = r15 & 7;
    float psum = 0.0f;
    f32x4 o[4] = {};
    const int kt0 = (qstart >= WINDOW) ? (qstart - WINDOW) : 0;

    for (int kt = kt0; kt <= qstart; kt += 64) {
        char* prow = (char*)plds + (((kt >> 6) & 1) << 13) + wave * 2048 + r15 * 128;
        // ---- QK^T for 64 keys ----
        bf16x8 ka[4], kc[4];
        #pragma unroll
        for (int t = 0; t < 4; t++) {
            const int kr = min(kt + t * 16 + r15, S_LEN - 1);
            const u16* kp = kb_ + ((size_t)kr * BATCH + b) * DMODEL
                          + ((h * DHEAD) ^ (SWZ ? ((kr & 7) << 7) : 0));
            ka[t] = *reinterpret_cast<const bf16x8*>(kp + g * 8);
            kc[t] = *reinterpret_cast<const bf16x8*>(kp + 32 + g * 8);
        }
        f32x4 st[4] = {};
        #pragma unroll
        for (int t = 0; t < 4; t++) {
            st[t] = __builtin_amdgcn_mfma_f32_16x16x32_bf16(ka[t], qf0, st[t], 0, 0, 0);
            st[t] = __builtin_amdgcn_mfma_f32_16x16x32_bf16(kc[t], qf1, st[t], 0, 0, 0);
        }
        // ---- p = masked ? 0 : exp(s); pack to LDS (bank-swizzled) ----
        #pragma unroll
        for (int t = 0; t < 4; t++) {
            float p[4];
            #pragma unroll
            for (int r = 0; r < 4; r++) {
                const int j = kt + t * 16 + g * 4 + r;
                const int d = i_glob - j;
                p[r] = (d < 0 || d >= WINDOW) ? 0.0f : __expf(st[t][r]);
                psum += p[r];
            }
            u32x2 w;
            w.x = cvtpk(p[0], p[1]);
            w.y = cvtpk(p[2], p[3]);
            *reinterpret_cast<u32x2*>(
                prow + ((((t << 1) + (g >> 1)) ^ q7) << 4) + ((g & 1) << 3)) = w;
        }
        const bf16x8 pf0 = *reinterpret_cast<const bf16x8*>(prow + ((g ^ q7) << 4));
        const bf16x8 pf1 = *reinterpret_cast<const bf16x8*>(prow + (((4 + g) ^ q7) << 4));
        // ---- PV over 64 keys ----
        int s0 = kt + g * 8;       if (s0 >= S_LEN) s0 = 0;
        int s1 = kt + 32 + g * 8;  if (s1 >= S_LEN) s1 = 0;
        #pragma unroll
        for (int c = 0; c < 4; c++) {
            const u16* vr = vbase + (size_t)(c * 16 + r15) * S_LEN;
            const bf16x8 vf0 = *reinterpret_cast<const bf16x8*>(vr + (s0 ^ sw7));
            const bf16x8 vf1 = *reinterpret_cast<const bf16x8*>(vr + (s1 ^ sw7));
            o[c] = __builtin_amdgcn_mfma_f32_16x16x32_bf16(vf0, pf0, o[c], 0, 0, 0);
            o[c] = __builtin_amdgcn_mfma_f32_16x16x32_bf16(vf1, pf1, o[c], 0, 0, 0);
        }
    }

    psum += __shfl_xor(psum, 16);
    psum += __shfl_xor(psum, 32);
    const float inv = 1.0f / psum;
    const int orow = i_glob * BATCH + b;
    const int osw = SWZ ? ((orow & 7) << 7) : 0;
    #pragma unroll
    for (int c = 0; c < 4; c++)
        #pragma unroll
        for (int r = 0; r < 4; r++) {
            const int dh = c * 16 + g * 4 + r;
            O[(size_t)orow * DMODEL + ((h * DHEAD + dh) ^ osw)] = f2b(o[c][r] * inv);
        }
}

extern "C" void kernel_launch(void* const* d_in, const int* in_sizes, int n_in,
                              void* d_out, int out_size, void* d_ws, size_t ws_size,
                              hipStream_t stream) {
    const float* x    = (const float*)d_in[0];
    const float* Wq   = (const float*)d_in[1];
    const float* bq   = (const float*)d_in[2];
    const float* Wk   = (const float*)d_in[3];
    const float* bk   = (const float*)d_in[4];
    const float* Wv   = (const float*)d_in[5];
    const float* bv   = (const float*)d_in[6];
    const float* Wo   = (const float*)d_in[7];
    const float* bo   = (const float*)d_in[8];
    const float* beta = (const float*)d_in[9];
    float* out = (float*)d_out;
    u16* ws = (u16*)d_ws;

    const size_t M4 = (size_t)MROWS * DMODEL;   // 4M elems
    u16* qbuf = (u16*)d_out;        // d_out[0:8MB]  (overwritten by final GEMM)
    u16* kbuf = (u16*)d_out + M4;   // d_out[8:16MB]
    u16* vtb  = ws;                 // 8 MB  V^T [b][h][dh][s]
    u16* abuf = ws + M4;            // 8 MB  attention out

    const int nattn = BATCH * NHEAD * (S_LEN / 16) / 4;  // 1024 blocks
    dim3 gqkv(MROWS / 128, 24);     // 768 blocks
    dim3 gout(MROWS / 128, 8);      // 256 blocks

    if (ws_size >= (size_t)32 * 1024 * 1024) {
        u16* xb  = ws + 2 * M4;             // 8 MB
        u16* wb  = ws + 3 * M4;             // 6 MB  [Wq;Wk;Wv] bf16
        u16* wob = ws + 3 * M4 + 3145728;   // 2 MB
        cast_all<<<4096, 256, 0, stream>>>(x, Wq, Wk, Wv, Wo, xb, wb, wob);
        gemm_qkv_s<<<gqkv, 256, 0, stream>>>(xb, wb, bq, bk, bv, beta, qbuf, kbuf, vtb);
        attn5<true><<<nattn, 256, 0, stream>>>(qbuf, kbuf, vtb, abuf);
        gemm_out_s<<<gout, 256, 0, stream>>>(abuf, wob, bo, out);
    } else {
        dim3 gout2(MROWS / 64, 8);
        gemm_qkv_t<false, false><<<gqkv, 256, 0, stream>>>(
            x, Wq, Wk, Wv, bq, bk, bv, beta, qbuf, kbuf, vtb);
        attn5<false><<<nattn, 256, 0, stream>>>(qbuf, kbuf, vtb, abuf);
        gemm_out_t<false><<<gout2, 256, 0, stream>>>(abuf, Wo, bo, out);
    }
}

// Round 12
// 92.969 us; speedup vs baseline: 1.4219x; 1.4219x over previous
//
#include <hip/hip_runtime.h>
#include <hip/hip_bf16.h>

#define S_LEN 2048
#define BATCH 2
#define DMODEL 1024
#define NHEAD 16
#define DHEAD 64
#define WINDOW 256
#define MROWS (S_LEN * BATCH)   // 4096

typedef unsigned short u16;
typedef unsigned int u32;
typedef __attribute__((ext_vector_type(8))) short bf16x8;
typedef __attribute__((ext_vector_type(4))) float f32x4;
typedef __attribute__((ext_vector_type(2))) unsigned int u32x2;

typedef const __attribute__((address_space(1))) void gvoid;
typedef __attribute__((address_space(3))) void lvoid;

__device__ __forceinline__ float b2f(u16 u) {
    union { unsigned int i; float f; } x; x.i = ((unsigned int)u) << 16; return x.f;
}
__device__ __forceinline__ u16 f2b(float f) {
    union { float f; unsigned int i; } x; x.f = f;
    unsigned int r = x.i + 0x7fffu + ((x.i >> 16) & 1u);
    return (u16)(r >> 16);
}
__device__ __forceinline__ u32 cvtpk(float a, float b) {
    u32 r; asm("v_cvt_pk_bf16_f32 %0, %1, %2" : "=v"(r) : "v"(a), "v"(b)); return r;
}
__device__ __forceinline__ bf16x8 ld8f(const float* __restrict__ p) {
    bf16x8 r;
    #pragma unroll
    for (int i = 0; i < 8; i++) r[i] = (short)f2b(p[i]);
    return r;
}
template<bool BF>
__device__ __forceinline__ bf16x8 ldrow(const void* __restrict__ base, size_t elemOff) {
    if constexpr (BF) return *reinterpret_cast<const bf16x8*>((const u16*)base + elemOff);
    else              return ld8f((const float*)base + elemOff);
}

// One streaming pass: cast x(4M) | Wq | Wk | Wv | Wo fp32 -> bf16 (8M elems).
__global__ __launch_bounds__(256) void cast_all(
    const float* __restrict__ x,  const float* __restrict__ Wq,
    const float* __restrict__ Wk, const float* __restrict__ Wv,
    const float* __restrict__ Wo,
    u16* __restrict__ xb, u16* __restrict__ wb, u16* __restrict__ wob)
{
    const size_t idx = ((size_t)blockIdx.x * 256 + threadIdx.x) * 8;
    const size_t M1 = 1048576;
    const float* src; u16* dst;
    if (idx < 4 * M1)      { src = x  + idx;            dst = xb  + idx; }
    else if (idx < 5 * M1) { src = Wq + (idx - 4 * M1); dst = wb  + (idx - 4 * M1); }
    else if (idx < 6 * M1) { src = Wk + (idx - 5 * M1); dst = wb  + (idx - 4 * M1); }
    else if (idx < 7 * M1) { src = Wv + (idx - 6 * M1); dst = wb  + (idx - 4 * M1); }
    else                   { src = Wo + (idx - 7 * M1); dst = wob + (idx - 7 * M1); }
    *reinterpret_cast<bf16x8*>(dst) = ld8f(src);
}

// ---------------- m97-structure staged GEMMs (round-9 verbatim) ----------------
__global__ __launch_bounds__(256) void gemm_qkv_s(
    const u16* __restrict__ A, const u16* __restrict__ Wall,
    const float* __restrict__ bq, const float* __restrict__ bk, const float* __restrict__ bv,
    const float* __restrict__ beta,
    u16* __restrict__ qbuf, u16* __restrict__ kbuf, u16* __restrict__ vt)
{
    __shared__ u16 lA[128 * 32];
    __shared__ u16 lB[128 * 32];
    const int tid = threadIdx.x;
    const int lane = tid & 63, wave = tid >> 6;
    const int r15 = lane & 15, g = lane >> 4;
    const int m0 = blockIdx.x * 128;
    const int range = blockIdx.y >> 3;                       // 0=Q 1=K 2=V
    const int n0 = (blockIdx.y & 7) * 128;                   // local col
    const u16* W = Wall + (size_t)range * DMODEL * DMODEL;
    const float* bias = (range == 0) ? bq : (range == 1) ? bk : bv;

    const int srow = tid >> 2;
    const int sslot = (tid & 3) ^ ((tid >> 3) & 3);          // pre-swizzled source slot
    const u16* aSrc = A + (size_t)(m0 + srow) * DMODEL + sslot * 8;
    const u16* wSrc = W + (size_t)(n0 + srow) * DMODEL + sslot * 8;
    const int ldsW = wave * 1024;                            // linear dest (byte)
    const int mrow = (wave >> 1) * 64, nrow = (wave & 1) * 64;
    const int swz = (g ^ ((r15 >> 1) & 3)) << 4;             // read-side XOR
    const char* lAr = (const char*)lA + swz;
    const char* lBr = (const char*)lB + swz;

    f32x4 acc[4][4] = {};
    for (int kk = 0; kk < DMODEL; kk += 32) {
        __syncthreads();
        #pragma unroll
        for (int ro = 0; ro < 2; ro++) {
            __builtin_amdgcn_global_load_lds(
                (gvoid*)(aSrc + (size_t)ro * 64 * DMODEL + kk),
                (lvoid*)((char*)lA + ro * 4096 + ldsW), 16, 0, 0);
            __builtin_amdgcn_global_load_lds(
                (gvoid*)(wSrc + (size_t)ro * 64 * DMODEL + kk),
                (lvoid*)((char*)lB + ro * 4096 + ldsW), 16, 0, 0);
        }
        __syncthreads();
        bf16x8 af[4], bf[4];
        #pragma unroll
        for (int mi = 0; mi < 4; mi++)
            af[mi] = *reinterpret_cast<const bf16x8*>(lAr + ((mrow + mi * 16 + r15) << 6));
        #pragma unroll
        for (int ni = 0; ni < 4; ni++)
            bf[ni] = *reinterpret_cast<const bf16x8*>(lBr + ((nrow + ni * 16 + r15) << 6));
        #pragma unroll
        for (int mi = 0; mi < 4; mi++)
            #pragma unroll
            for (int ni = 0; ni < 4; ni++)
                acc[mi][ni] = __builtin_amdgcn_mfma_f32_16x16x32_bf16(
                    af[mi], bf[ni], acc[mi][ni], 0, 0, 0);
    }
    #pragma unroll
    for (int ni = 0; ni < 4; ni++) {
        const int col = n0 + nrow + ni * 16 + r15;           // 0..1023
        const float bv_ = bias[col];
        float scale = 1.0f;
        if (range == 0) scale = 1.0f / (8.0f * __expf(beta[col >> 6]));
        #pragma unroll
        for (int mi = 0; mi < 4; mi++)
            #pragma unroll
            for (int r = 0; r < 4; r++) {
                const int row = m0 + mrow + mi * 16 + g * 4 + r;
                const float val = acc[mi][ni][r] + bv_;
                if (range == 0) {
                    qbuf[(size_t)row * DMODEL + col] = f2b(val * scale);
                } else if (range == 1) {
                    kbuf[(size_t)row * DMODEL + col] = f2b(val);
                } else {
                    const int b = row & 1, s = row >> 1;
                    vt[((size_t)(b * NHEAD + (col >> 6)) * DHEAD + (col & 63)) * S_LEN + s]
                        = f2b(val);
                }
            }
    }
}

__global__ __launch_bounds__(256) void gemm_out_s(
    const u16* __restrict__ A, const u16* __restrict__ W,
    const float* __restrict__ bias, float* __restrict__ C)
{
    __shared__ u16 lA[128 * 32];
    __shared__ u16 lB[128 * 32];
    const int tid = threadIdx.x;
    const int lane = tid & 63, wave = tid >> 6;
    const int r15 = lane & 15, g = lane >> 4;
    const int m0 = blockIdx.x * 128;
    const int n0 = blockIdx.y * 128;

    const int srow = tid >> 2;
    const int sslot = (tid & 3) ^ ((tid >> 3) & 3);
    const u16* aSrc = A + (size_t)(m0 + srow) * DMODEL + sslot * 8;
    const u16* wSrc = W + (size_t)(n0 + srow) * DMODEL + sslot * 8;
    const int ldsW = wave * 1024;
    const int mrow = (wave >> 1) * 64, nrow = (wave & 1) * 64;
    const int swz = (g ^ ((r15 >> 1) & 3)) << 4;
    const char* lAr = (const char*)lA + swz;
    const char* lBr = (const char*)lB + swz;

    f32x4 acc[4][4] = {};
    for (int kk = 0; kk < DMODEL; kk += 32) {
        __syncthreads();
        #pragma unroll
        for (int ro = 0; ro < 2; ro++) {
            __builtin_amdgcn_global_load_lds(
                (gvoid*)(aSrc + (size_t)ro * 64 * DMODEL + kk),
                (lvoid*)((char*)lA + ro * 4096 + ldsW), 16, 0, 0);
            __builtin_amdgcn_global_load_lds(
                (gvoid*)(wSrc + (size_t)ro * 64 * DMODEL + kk),
                (lvoid*)((char*)lB + ro * 4096 + ldsW), 16, 0, 0);
        }
        __syncthreads();
        bf16x8 af[4], bf[4];
        #pragma unroll
        for (int mi = 0; mi < 4; mi++)
            af[mi] = *reinterpret_cast<const bf16x8*>(lAr + ((mrow + mi * 16 + r15) << 6));
        #pragma unroll
        for (int ni = 0; ni < 4; ni++)
            bf[ni] = *reinterpret_cast<const bf16x8*>(lBr + ((nrow + ni * 16 + r15) << 6));
        #pragma unroll
        for (int mi = 0; mi < 4; mi++)
            #pragma unroll
            for (int ni = 0; ni < 4; ni++)
                acc[mi][ni] = __builtin_amdgcn_mfma_f32_16x16x32_bf16(
                    af[mi], bf[ni], acc[mi][ni], 0, 0, 0);
    }
    #pragma unroll
    for (int ni = 0; ni < 4; ni++) {
        const int col = n0 + nrow + ni * 16 + r15;
        const float bv_ = bias[col];
        #pragma unroll
        for (int mi = 0; mi < 4; mi++)
            #pragma unroll
            for (int r = 0; r < 4; r++) {
                const int row = m0 + mrow + mi * 16 + g * 4 + r;
                C[(size_t)row * DMODEL + col] = acc[mi][ni][r] + bv_;
            }
    }
}

// ---------------- fallback (fp32 direct) GEMMs ----------------
template<bool ABF, bool WBF>
__global__ __launch_bounds__(256) void gemm_qkv_t(
    const void* __restrict__ A_,
    const void* __restrict__ Wq_, const void* __restrict__ Wk_, const void* __restrict__ Wv_,
    const float* __restrict__ bq, const float* __restrict__ bk, const float* __restrict__ bv,
    const float* __restrict__ beta,
    u16* __restrict__ qbuf, u16* __restrict__ kbuf, u16* __restrict__ vt)
{
    const int lane = threadIdx.x & 63;
    const int wave = threadIdx.x >> 6;
    const int r15 = lane & 15, g = lane >> 4;
    const int m0 = blockIdx.x * 128 + (wave >> 1) * 64;
    const int range = blockIdx.y >> 3;
    const int n0 = (blockIdx.y & 7) * 128 + (wave & 1) * 64;
    const void* W_ = (range == 0) ? Wq_ : (range == 1) ? Wk_ : Wv_;
    const float* bias = (range == 0) ? bq : (range == 1) ? bk : bv;
    const size_t aBase = (size_t)(m0 + r15) * DMODEL + g * 8;
    const size_t wBase = (size_t)(n0 + r15) * DMODEL + g * 8;
    f32x4 acc[4][4] = {};
    for (int k = 0; k < DMODEL; k += 32) {
        bf16x8 af[4], bf[4];
        #pragma unroll
        for (int mi = 0; mi < 4; mi++) af[mi] = ldrow<ABF>(A_, aBase + (size_t)mi * 16 * DMODEL + k);
        #pragma unroll
        for (int ni = 0; ni < 4; ni++) bf[ni] = ldrow<WBF>(W_, wBase + (size_t)ni * 16 * DMODEL + k);
        #pragma unroll
        for (int mi = 0; mi < 4; mi++)
            #pragma unroll
            for (int ni = 0; ni < 4; ni++)
                acc[mi][ni] = __builtin_amdgcn_mfma_f32_16x16x32_bf16(
                    af[mi], bf[ni], acc[mi][ni], 0, 0, 0);
    }
    #pragma unroll
    for (int ni = 0; ni < 4; ni++) {
        const int col = n0 + ni * 16 + r15;
        const float bv_ = bias[col];
        float scale = 1.0f;
        if (range == 0) scale = 1.0f / (8.0f * __expf(beta[col >> 6]));
        #pragma unroll
        for (int mi = 0; mi < 4; mi++)
            #pragma unroll
            for (int r = 0; r < 4; r++) {
                const int row = m0 + mi * 16 + g * 4 + r;
                const float val = acc[mi][ni][r] + bv_;
                if (range == 0) {
                    qbuf[(size_t)row * DMODEL + col] = f2b(val * scale);
                } else if (range == 1) {
                    kbuf[(size_t)row * DMODEL + col] = f2b(val);
                } else {
                    const int b = row & 1, s = row >> 1;
                    vt[((size_t)(b * NHEAD + (col >> 6)) * DHEAD + (col & 63)) * S_LEN + s]
                        = f2b(val);
                }
            }
    }
}

template<bool WBF>
__global__ __launch_bounds__(256) void gemm_out_t(
    const u16* __restrict__ A, const void* __restrict__ W_,
    const float* __restrict__ bias, float* __restrict__ C)
{
    const int lane = threadIdx.x & 63;
    const int wave = threadIdx.x >> 6;
    const int r15 = lane & 15, g = lane >> 4;
    const int m0 = blockIdx.x * 64 + (wave >> 1) * 32;
    const int n0 = blockIdx.y * 128 + (wave & 1) * 64;
    const u16* a0 = A + (size_t)(m0 + r15) * DMODEL + g * 8;
    const size_t wBase = (size_t)(n0 + r15) * DMODEL + g * 8;
    f32x4 acc[2][4] = {};
    for (int k = 0; k < DMODEL; k += 32) {
        bf16x8 af[2], bf[4];
        #pragma unroll
        for (int mi = 0; mi < 2; mi++)
            af[mi] = *reinterpret_cast<const bf16x8*>(a0 + (size_t)mi * 16 * DMODEL + k);
        #pragma unroll
        for (int ni = 0; ni < 4; ni++) bf[ni] = ldrow<WBF>(W_, wBase + (size_t)ni * 16 * DMODEL + k);
        #pragma unroll
        for (int mi = 0; mi < 2; mi++)
            #pragma unroll
            for (int ni = 0; ni < 4; ni++)
                acc[mi][ni] = __builtin_amdgcn_mfma_f32_16x16x32_bf16(
                    af[mi], bf[ni], acc[mi][ni], 0, 0, 0);
    }
    #pragma unroll
    for (int ni = 0; ni < 4; ni++) {
        const int col = n0 + ni * 16 + r15;
        const float bv_ = bias[col];
        #pragma unroll
        for (int mi = 0; mi < 2; mi++)
            #pragma unroll
            for (int r = 0; r < 4; r++) {
                const int row = m0 + mi * 16 + g * 4 + r;
                C[(size_t)row * DMODEL + col] = acc[mi][ni][r] + bv_;
            }
    }
}

// Sliding-window attention v6: block = (b, h, 64-query band); 4 waves share
// cooperatively LDS-staged K/V chunk tiles (coalesced global_load_lds, both-sides
// XOR bank swizzle). Per-wave math identical to attn3 (no online softmax; bounded
// scores). XCD-chunked grid keeps each (b,h)'s KV in one L2.
__global__ __launch_bounds__(256) void attn6(
    const u16* __restrict__ qb, const u16* __restrict__ kb_,
    const u16* __restrict__ vt, u16* __restrict__ O)
{
    __shared__ u16 lK[64 * 64];          // 8KB: 64 keys x 128B (dh), swizzled slots
    __shared__ u16 lV[64 * 64];          // 8KB: 64 dh  x 128B (keys), swizzled slots
    __shared__ u16 plds[4][16][64];      // 8KB: per-wave P transpose
    const int tid  = threadIdx.x;
    const int lane = tid & 63;
    const int wave = tid >> 6;
    const int bid  = blockIdx.x;
    const int sbid = (bid & 7) * 128 + (bid >> 3);     // XCD-chunked (1024%8==0)
    const int qblk = sbid & 31;                        // 64-query band
    const int h    = (sbid >> 5) & (NHEAD - 1);
    const int b    = sbid >> 9;
    const int qt = qblk * 4 + wave;
    const int qstart = qt * 16;
    const int r15 = lane & 15, g = lane >> 4;
    const int i_glob = qstart + r15;

    const u16* qrow = qb + ((size_t)i_glob * BATCH + b) * DMODEL + h * DHEAD;
    const bf16x8 qf0 = *reinterpret_cast<const bf16x8*>(qrow + g * 8);
    const bf16x8 qf1 = *reinterpret_cast<const bf16x8*>(qrow + 32 + g * 8);

    char* prow = (char*)plds + wave * 2048 + r15 * 128;
    const int q7 = r15 & 7;

    // staging lane roles (per global_load_lds instr i: rows i*32 + wave*8 + lane/8)
    const int sr_lo = wave * 8 + (lane >> 3);          // i=0 row
    const int scol8 = lane & 7;

    float psum = 0.0f;
    f32x4 o[4] = {};

    #pragma unroll
    for (int c = 0; c < 5; c++) {
        const int kstart = qblk * 64 - WINDOW + c * 64;
        if (kstart < -63) continue;                    // block-uniform skip

        __syncthreads();                               // protect LDS reuse
        #pragma unroll
        for (int i = 0; i < 2; i++) {
            const int srow = i * 32 + sr_lo;           // 0..63
            const int sc = scol8 ^ (srow & 7);         // pre-swizzled source slot
            const int ks = min(max(kstart + srow, 0), S_LEN - 1);
            __builtin_amdgcn_global_load_lds(
                (gvoid*)(kb_ + ((size_t)ks * BATCH + b) * DMODEL + h * DHEAD + sc * 8),
                (lvoid*)((char*)lK + i * 4096 + wave * 1024), 16, 0, 0);
            const int vs = min(max(kstart + sc * 8, 0), S_LEN - 8);
            __builtin_amdgcn_global_load_lds(
                (gvoid*)(vt + ((size_t)(b * NHEAD + h) * DHEAD + srow) * S_LEN + vs),
                (lvoid*)((char*)lV + i * 4096 + wave * 1024), 16, 0, 0);
        }
        __syncthreads();                               // staging complete (vmcnt drained)

        // ---- QK^T for 64 keys from LDS ----
        f32x4 st[4] = {};
        #pragma unroll
        for (int t = 0; t < 4; t++) {
            const int R = t * 16 + r15;
            const bf16x8 ka = *reinterpret_cast<const bf16x8*>(
                lK + R * 64 + ((g ^ (R & 7)) << 3));
            const bf16x8 kc = *reinterpret_cast<const bf16x8*>(
                lK + R * 64 + (((4 + g) ^ (R & 7)) << 3));
            st[t] = __builtin_amdgcn_mfma_f32_16x16x32_bf16(ka, qf0, st[t], 0, 0, 0);
            st[t] = __builtin_amdgcn_mfma_f32_16x16x32_bf16(kc, qf1, st[t], 0, 0, 0);
        }

        // ---- p = masked ? 0 : exp(s); pack to private P-LDS ----
        #pragma unroll
        for (int t = 0; t < 4; t++) {
            float p[4];
            #pragma unroll
            for (int r = 0; r < 4; r++) {
                const int j = kstart + t * 16 + g * 4 + r;
                const int d = i_glob - j;
                p[r] = (j < 0 || d < 0 || d >= WINDOW) ? 0.0f : __expf(st[t][r]);
                psum += p[r];
            }
            u32x2 w;
            w.x = cvtpk(p[0], p[1]);
            w.y = cvtpk(p[2], p[3]);
            *reinterpret_cast<u32x2*>(
                prow + ((((t << 1) + (g >> 1)) ^ q7) << 4) + ((g & 1) << 3)) = w;
        }
        const bf16x8 pf0 = *reinterpret_cast<const bf16x8*>(prow + ((g ^ q7) << 4));
        const bf16x8 pf1 = *reinterpret_cast<const bf16x8*>(prow + (((4 + g) ^ q7) << 4));

        // ---- PV over 64 keys from LDS ----
        #pragma unroll
        for (int c4 = 0; c4 < 4; c4++) {
            const int R = c4 * 16 + r15;
            const bf16x8 vf0 = *reinterpret_cast<const bf16x8*>(
                lV + R * 64 + ((g ^ (R & 7)) << 3));
            const bf16x8 vf1 = *reinterpret_cast<const bf16x8*>(
                lV + R * 64 + (((4 + g) ^ (R & 7)) << 3));
            o[c4] = __builtin_amdgcn_mfma_f32_16x16x32_bf16(vf0, pf0, o[c4], 0, 0, 0);
            o[c4] = __builtin_amdgcn_mfma_f32_16x16x32_bf16(vf1, pf1, o[c4], 0, 0, 0);
        }
    }

    psum += __shfl_xor(psum, 16);
    psum += __shfl_xor(psum, 32);
    const float inv = 1.0f / psum;
    #pragma unroll
    for (int c4 = 0; c4 < 4; c4++)
        #pragma unroll
        for (int r = 0; r < 4; r++) {
            const int dh = c4 * 16 + g * 4 + r;
            O[((size_t)i_glob * BATCH + b) * DMODEL + h * DHEAD + dh] = f2b(o[c4][r] * inv);
        }
}

extern "C" void kernel_launch(void* const* d_in, const int* in_sizes, int n_in,
                              void* d_out, int out_size, void* d_ws, size_t ws_size,
                              hipStream_t stream) {
    const float* x    = (const float*)d_in[0];
    const float* Wq   = (const float*)d_in[1];
    const float* bq   = (const float*)d_in[2];
    const float* Wk   = (const float*)d_in[3];
    const float* bk   = (const float*)d_in[4];
    const float* Wv   = (const float*)d_in[5];
    const float* bv   = (const float*)d_in[6];
    const float* Wo   = (const float*)d_in[7];
    const float* bo   = (const float*)d_in[8];
    const float* beta = (const float*)d_in[9];
    float* out = (float*)d_out;
    u16* ws = (u16*)d_ws;

    const size_t M4 = (size_t)MROWS * DMODEL;   // 4M elems
    u16* qbuf = (u16*)d_out;        // d_out[0:8MB]  (overwritten by final GEMM)
    u16* kbuf = (u16*)d_out + M4;   // d_out[8:16MB]
    u16* vtb  = ws;                 // 8 MB  V^T [b][h][dh][s]
    u16* abuf = ws + M4;            // 8 MB  attention out

    const int nattn = BATCH * NHEAD * (S_LEN / 64);      // 1024 blocks
    dim3 gqkv(MROWS / 128, 24);     // 768 blocks
    dim3 gout(MROWS / 128, 8);      // 256 blocks

    if (ws_size >= (size_t)32 * 1024 * 1024) {
        u16* xb  = ws + 2 * M4;             // 8 MB
        u16* wb  = ws + 3 * M4;             // 6 MB  [Wq;Wk;Wv] bf16
        u16* wob = ws + 3 * M4 + 3145728;   // 2 MB
        cast_all<<<4096, 256, 0, stream>>>(x, Wq, Wk, Wv, Wo, xb, wb, wob);
        gemm_qkv_s<<<gqkv, 256, 0, stream>>>(xb, wb, bq, bk, bv, beta, qbuf, kbuf, vtb);
        attn6<<<nattn, 256, 0, stream>>>(qbuf, kbuf, vtb, abuf);
        gemm_out_s<<<gout, 256, 0, stream>>>(abuf, wob, bo, out);
    } else {
        dim3 gout2(MROWS / 64, 8);
        gemm_qkv_t<false, false><<<gqkv, 256, 0, stream>>>(
            x, Wq, Wk, Wv, bq, bk, bv, beta, qbuf, kbuf, vtb);
        attn6<<<nattn, 256, 0, stream>>>(qbuf, kbuf, vtb, abuf);
        gemm_out_t<false><<<gout2, 256, 0, stream>>>(abuf, Wo, bo, out);
    }
}